// Round 8
// baseline (352.584 us; speedup 1.0000x reference)
//
#include <hip/hip_runtime.h>
#include <hip/hip_fp16.h>

// ---------------------------------------------------------------------------
// EdgeClassifierGNN: 2x GCNConv (128->64->64, sym-norm, self-loops) + edge MLP
// Round 8: k_edge was LDS-pipe-bound (288 ds_bpermute/wave from __shfl).
//  - ea broadcast: per-wave LDS tile + 2 broadcast ds_read_b128/pass (was 8 shfl)
//  - 16-lane reduce: DPP row_ror rotate-allreduce (pure VALU, was 8 shfl/pass)
//  - k_agg reverted to R6 config (R7's 8-deep/(256,4) cost ~17us occupancy)
// ---------------------------------------------------------------------------

__device__ __forceinline__ void fma4(float4& a, float s, const float4& b) {
    a.x = fmaf(s, b.x, a.x);
    a.y = fmaf(s, b.y, a.y);
    a.z = fmaf(s, b.z, a.z);
    a.w = fmaf(s, b.w, a.w);
}

__device__ __forceinline__ float4 relu4(float4 v) {
    v.x = fmaxf(v.x, 0.f); v.y = fmaxf(v.y, 0.f);
    v.z = fmaxf(v.z, 0.f); v.w = fmaxf(v.w, 0.f);
    return v;
}

__device__ __forceinline__ void store4(float* C, size_t idx, float4 v) {
    *reinterpret_cast<float4*>(C + idx) = v;
}
__device__ __forceinline__ void store4(__half* C, size_t idx, float4 v) {
    __half2 lo = __floats2half2_rn(v.x, v.y);
    __half2 hi = __floats2half2_rn(v.z, v.w);
    uint2 raw;
    raw.x = *reinterpret_cast<unsigned*>(&lo);
    raw.y = *reinterpret_cast<unsigned*>(&hi);
    *reinterpret_cast<uint2*>(C + idx) = raw;
}

// DPP rotate-allreduce over each 16-lane row: after 4 steps every lane holds
// the row sum. row_ror:k ctrl = 0x120+k (rotation wraps within the row).
template <int CTRL>
__device__ __forceinline__ float dpp_radd(float x) {
    int y = __builtin_amdgcn_update_dpp(0, __float_as_int(x), CTRL, 0xF, 0xF, false);
    return x + __int_as_float(y);
}
__device__ __forceinline__ float row16_allreduce(float x) {
    x = dpp_radd<0x128>(x);  // + ror8
    x = dpp_radd<0x124>(x);  // + ror4
    x = dpp_radd<0x122>(x);  // + ror2
    x = dpp_radd<0x121>(x);  // + ror1
    return x;
}

// cnt[d]++ per edge; rank[e] = arrival order of e within its dst bucket
__global__ void k_count(const int* __restrict__ dst, int* __restrict__ cnt,
                        int* __restrict__ rank, int E) {
    int e = blockIdx.x * 256 + threadIdx.x;
    if (e < E) rank[e] = atomicAdd(&cnt[dst[e]], 1);
}

// block sums for scan + dinv = rsqrt(cnt+1) (fused)
__global__ void k_bsum(const int* __restrict__ cnt, int* __restrict__ bsum,
                       float* __restrict__ dinv, int N) {
    int i = blockIdx.x * 256 + threadIdx.x;
    int v = (i < N) ? cnt[i] : 0;
    if (i < N) dinv[i] = rsqrtf((float)v + 1.0f);
    int r = v;
#pragma unroll
    for (int d = 1; d < 64; d <<= 1) r += __shfl_xor(r, d);
    __shared__ int ws[4];
    if ((threadIdx.x & 63) == 0) ws[threadIdx.x >> 6] = r;
    __syncthreads();
    if (threadIdx.x == 0) bsum[blockIdx.x] = ws[0] + ws[1] + ws[2] + ws[3];
}

// in-place exclusive scan of bsum[0..nb), nb <= 256, single block
__global__ void k_scanb(int* __restrict__ bsum, int nb) {
    int t = threadIdx.x;
    int lane = t & 63, w = t >> 6;
    int v = (t < nb) ? bsum[t] : 0;
    int x = v;
#pragma unroll
    for (int d = 1; d < 64; d <<= 1) {
        int y = __shfl_up(x, d);
        if (lane >= d) x += y;
    }
    __shared__ int ws[4];
    if (lane == 63) ws[w] = x;
    __syncthreads();
    int woff = 0;
    for (int j = 0; j < w; j++) woff += ws[j];
    if (t < nb) bsum[t] = woff + x - v;
}

// row_ptr[i] = bsum[blk] + exclusive_scan_within_block(cnt); row_ptr[N] = E
__global__ void k_scan3(const int* __restrict__ cnt, const int* __restrict__ bsum,
                        int* __restrict__ row_ptr, int N, int E) {
    int t = threadIdx.x, b = blockIdx.x;
    int i = b * 256 + t;
    int lane = t & 63, w = t >> 6;
    int v = (i < N) ? cnt[i] : 0;
    int x = v;
#pragma unroll
    for (int d = 1; d < 64; d <<= 1) {
        int y = __shfl_up(x, d);
        if (lane >= d) x += y;
    }
    __shared__ int ws[4];
    if (lane == 63) ws[w] = x;
    __syncthreads();
    int woff = 0;
    for (int j = 0; j < w; j++) woff += ws[j];
    if (i < N) row_ptr[i] = bsum[b] + woff + x - v;
    if (i == 0) row_ptr[N] = E;
}

// atomic-free: csr_src[row_ptr[dst[e]] + rank[e]] = src[e]
__global__ void k_fill(const int* __restrict__ src, const int* __restrict__ dst,
                       const int* __restrict__ row_ptr, const int* __restrict__ rank,
                       int* __restrict__ csr_src, int E) {
    int e = blockIdx.x * 256 + threadIdx.x;
    if (e >= E) return;
    csr_src[row_ptr[dst[e]] + rank[e]] = src[e];
}

// C[M x 64] = (SCALE? dinv[row] : 1) * (op(A[M x K]) @ B[K x 64]); op=relu if RELU_A
template<int K, bool RELU_A, bool SCALE, typename OutT>
__global__ __launch_bounds__(256) void k_gemm(const float* __restrict__ A,
                                              const float* __restrict__ B,
                                              const float* __restrict__ dinv,
                                              OutT* __restrict__ C, int M) {
    constexpr int AS = K + 4;
    __shared__ float As[64 * AS];
    __shared__ float Bs[64 * 64];
    const int t = threadIdx.x;
    const int r0 = blockIdx.x * 64;

    constexpr int C4 = K / 4;
    for (int idx = t; idx < 64 * C4; idx += 256) {
        int row = idx / C4, c4 = idx % C4;
        float4 v = make_float4(0.f, 0.f, 0.f, 0.f);
        if (r0 + row < M)
            v = reinterpret_cast<const float4*>(A + (size_t)(r0 + row) * K)[c4];
        if (RELU_A) v = relu4(v);
        *reinterpret_cast<float4*>(&As[row * AS + 4 * c4]) = v;
    }

    const int tx = t & 15, ty = t >> 4;
    float4 acc[4];
    acc[0] = acc[1] = acc[2] = acc[3] = make_float4(0.f, 0.f, 0.f, 0.f);

    for (int c = 0; c < K / 64; c++) {
        __syncthreads();
        for (int idx = t; idx < 64 * 16; idx += 256)
            reinterpret_cast<float4*>(Bs)[idx] =
                reinterpret_cast<const float4*>(B + (size_t)c * 64 * 64)[idx];
        __syncthreads();
#pragma unroll
        for (int k0 = 0; k0 < 64; k0 += 4) {
            float4 b0 = *reinterpret_cast<const float4*>(&Bs[(k0 + 0) * 64 + 4 * tx]);
            float4 b1 = *reinterpret_cast<const float4*>(&Bs[(k0 + 1) * 64 + 4 * tx]);
            float4 b2 = *reinterpret_cast<const float4*>(&Bs[(k0 + 2) * 64 + 4 * tx]);
            float4 b3 = *reinterpret_cast<const float4*>(&Bs[(k0 + 3) * 64 + 4 * tx]);
#pragma unroll
            for (int i = 0; i < 4; i++) {
                float4 a = *reinterpret_cast<const float4*>(
                    &As[(4 * ty + i) * AS + c * 64 + k0]);
                fma4(acc[i], a.x, b0);
                fma4(acc[i], a.y, b1);
                fma4(acc[i], a.z, b2);
                fma4(acc[i], a.w, b3);
            }
        }
    }

#pragma unroll
    for (int i = 0; i < 4; i++) {
        int row = r0 + 4 * ty + i;
        if (row < M) {
            float4 o = acc[i];
            if (SCALE) {
                float di = dinv[row];
                o = make_float4(di * o.x, di * o.y, di * o.z, di * o.w);
            }
            store4(C, (size_t)row * 64 + 4 * tx, o);
        }
    }
}

// Fused projections: C0 = relu(A)@B0, C1 = relu(A)@B1 (A staged once), fp16 out
__global__ __launch_bounds__(256) void k_proj(const float* __restrict__ A,
                                              const float* __restrict__ B0,
                                              const float* __restrict__ B1,
                                              __half* __restrict__ C0,
                                              __half* __restrict__ C1, int M) {
    constexpr int AS = 68;
    __shared__ float As[64 * AS];
    __shared__ float Bs[64 * 64];
    const int t = threadIdx.x;
    const int r0 = blockIdx.x * 64;

    for (int idx = t; idx < 64 * 16; idx += 256) {
        int row = idx / 16, c4 = idx % 16;
        float4 v = make_float4(0.f, 0.f, 0.f, 0.f);
        if (r0 + row < M)
            v = relu4(reinterpret_cast<const float4*>(A + (size_t)(r0 + row) * 64)[c4]);
        *reinterpret_cast<float4*>(&As[row * AS + 4 * c4]) = v;
    }

    const int tx = t & 15, ty = t >> 4;
    for (int m = 0; m < 2; m++) {
        const float* B = m ? B1 : B0;
        __half* C = m ? C1 : C0;
        __syncthreads();
        for (int idx = t; idx < 64 * 16; idx += 256)
            reinterpret_cast<float4*>(Bs)[idx] =
                reinterpret_cast<const float4*>(B)[idx];
        __syncthreads();
        float4 acc[4];
        acc[0] = acc[1] = acc[2] = acc[3] = make_float4(0.f, 0.f, 0.f, 0.f);
#pragma unroll
        for (int k0 = 0; k0 < 64; k0 += 4) {
            float4 b0 = *reinterpret_cast<const float4*>(&Bs[(k0 + 0) * 64 + 4 * tx]);
            float4 b1 = *reinterpret_cast<const float4*>(&Bs[(k0 + 1) * 64 + 4 * tx]);
            float4 b2 = *reinterpret_cast<const float4*>(&Bs[(k0 + 2) * 64 + 4 * tx]);
            float4 b3 = *reinterpret_cast<const float4*>(&Bs[(k0 + 3) * 64 + 4 * tx]);
#pragma unroll
            for (int i = 0; i < 4; i++) {
                float4 a = *reinterpret_cast<const float4*>(&As[(4 * ty + i) * AS + k0]);
                fma4(acc[i], a.x, b0);
                fma4(acc[i], a.y, b1);
                fma4(acc[i], a.z, b2);
                fma4(acc[i], a.w, b3);
            }
        }
#pragma unroll
        for (int i = 0; i < 4; i++) {
            int row = r0 + 4 * ty + i;
            if (row < M) store4(C, (size_t)row * 64 + 4 * tx, acc[i]);
        }
    }
}

// 4 nodes/wave, 16 lanes/node, uint2 (4 fp16)/lane, 4-deep gather pipeline
// (R6 config): out[d] = bias + dinv[d]*(A16[d] + sum_s A16[s])
__global__ __launch_bounds__(256) void k_agg(const __half* __restrict__ A16,
                                             const int* __restrict__ row_ptr,
                                             const int* __restrict__ csr_src,
                                             const float* __restrict__ dinv,
                                             const float* __restrict__ bias,
                                             float* __restrict__ out, int N) {
    int gw = (blockIdx.x * 256 + threadIdx.x) >> 6;  // global wave
    int sub = (threadIdx.x >> 4) & 3;
    int l = threadIdx.x & 15;
    int node = gw * 4 + sub;
    if (node >= N) return;
    const uint2* A4 = reinterpret_cast<const uint2*>(A16);  // row = 16 uint2

    int beg = row_ptr[node], end = row_ptr[node + 1];
    uint2 selfv = A4[(size_t)node * 16 + l];
    float2 a0 = __half22float2(*reinterpret_cast<__half2*>(&selfv.x));
    float2 a1 = __half22float2(*reinterpret_cast<__half2*>(&selfv.y));
    float4 acc = make_float4(a0.x, a0.y, a1.x, a1.y);

    for (int p = beg; p < end; p += 16) {
        int m = min(16, end - p);
        int sl = (p + l < end) ? csr_src[p + l] : 0;
        int j = 0;
        for (; j + 3 < m; j += 4) {
            int s0 = __shfl(sl, j + 0, 16);
            int s1 = __shfl(sl, j + 1, 16);
            int s2 = __shfl(sl, j + 2, 16);
            int s3 = __shfl(sl, j + 3, 16);
            uint2 u0 = A4[(size_t)s0 * 16 + l];
            uint2 u1 = A4[(size_t)s1 * 16 + l];
            uint2 u2 = A4[(size_t)s2 * 16 + l];
            uint2 u3 = A4[(size_t)s3 * 16 + l];
#define ACC(u)                                                          \
    {                                                                   \
        float2 f0 = __half22float2(*reinterpret_cast<__half2*>(&u.x));  \
        float2 f1 = __half22float2(*reinterpret_cast<__half2*>(&u.y));  \
        acc.x += f0.x; acc.y += f0.y; acc.z += f1.x; acc.w += f1.y;     \
    }
            ACC(u0) ACC(u1) ACC(u2) ACC(u3)
        }
        for (; j < m; j++) {
            int s0 = __shfl(sl, j, 16);
            uint2 u0 = A4[(size_t)s0 * 16 + l];
            ACC(u0)
        }
#undef ACC
    }
    float di = dinv[node];
    float4 bb = *reinterpret_cast<const float4*>(&bias[4 * l]);
    float4 o = make_float4(fmaf(di, acc.x, bb.x), fmaf(di, acc.y, bb.y),
                           fmaf(di, acc.z, bb.z), fmaf(di, acc.w, bb.w));
    *reinterpret_cast<float4*>(&out[(size_t)node * 64 + 4 * l]) = o;
}

// Edge epilogue: out[e] = relu(Ps[s] + Pd[d] + ea@We + bm1) @ Wm2 + bm2
// Per wave: 64 edges. ea staged in per-wave LDS (broadcast b128 reads),
// DPP rotate-allreduce for the 16-lane reduction, 4-deep gather pipeline.
__global__ __launch_bounds__(256, 4) void k_edge(
    const __half* __restrict__ Ps, const __half* __restrict__ Pd,
    const int* __restrict__ src, const int* __restrict__ dst,
    const float* __restrict__ ea, const float* __restrict__ We,
    const float* __restrict__ bm1, const float* __restrict__ Wm2,
    const float* __restrict__ bm2, float* __restrict__ out, int E) {
    __shared__ int eabuf[4 * 768];  // per wave: 64 edges x 12 words (48B rows)
    const int t = threadIdx.x;
    const int lane = t & 63;
    const int wv = t >> 6;
    const int wid = (blockIdx.x * 256 + t) >> 6;
    const int li = lane & 15, g = lane >> 4;
    const int e0 = wid * 64;
    if (e0 >= E) return;
    int* eaw = eabuf + wv * 768;

    // stage ea tile (64 edges x 16 floats) -> LDS fp16; coalesced global loads
    {
        size_t eabase = (size_t)e0 * 16;
#pragma unroll
        for (int it = 0; it < 4; it++) {
            int flat = 64 * it + lane;  // 0..255 float4s
            int le = flat >> 2, q = flat & 3;
            float4 f = *reinterpret_cast<const float4*>(ea + eabase + 4 * flat);
            __half2 a = __floats2half2_rn(f.x, f.y);
            __half2 b = __floats2half2_rn(f.z, f.w);
            uint2 pk;
            pk.x = *reinterpret_cast<unsigned*>(&a);
            pk.y = *reinterpret_cast<unsigned*>(&b);
            *reinterpret_cast<uint2*>(eaw + le * 12 + q * 2) = pk;
        }
    }

    // We cols 4li..4li+3 packed fp16
    __half2 wc[16][2];
#pragma unroll
    for (int k = 0; k < 16; k++) {
        float4 w = *reinterpret_cast<const float4*>(&We[k * 64 + 4 * li]);
        wc[k][0] = __floats2half2_rn(w.x, w.y);
        wc[k][1] = __floats2half2_rn(w.z, w.w);
    }
    float4 w2a = *reinterpret_cast<const float4*>(&Wm2[8 * li]);
    float4 w2b = *reinterpret_cast<const float4*>(&Wm2[8 * li + 4]);
    float4 bb = *reinterpret_cast<const float4*>(&bm1[4 * li]);
    float c0 = bm2[0], c1 = bm2[1];

    // hoist 64 edge indices (coalesced)
    int ecl = min(e0 + lane, E - 1);
    int sv = src[ecl], dv = dst[ecl];

    uint2 rs[4], rd[4];
#define ISSUE(p, slot)                                                      \
    {                                                                       \
        int idx = 4 * (p) + g;                                              \
        int s = __shfl(sv, idx);                                            \
        int d = __shfl(dv, idx);                                            \
        rs[slot] = *reinterpret_cast<const uint2*>(&Ps[(size_t)s * 64 + 4 * li]); \
        rd[slot] = *reinterpret_cast<const uint2*>(&Pd[(size_t)d * 64 + 4 * li]); \
    }
    ISSUE(0, 0) ISSUE(1, 1) ISSUE(2, 2) ISSUE(3, 3)

#pragma unroll
    for (int p = 0; p < 16; p++) {
        const int slot = p & 3;
        uint2 crs = rs[slot], crd = rd[slot];
        if (p + 4 < 16) ISSUE(p + 4, slot)

        // q = ea[e] @ We: ea fp16 pairs via broadcast LDS reads (group-uniform)
        int eloc = 4 * p + g;
        uint4 r0 = *reinterpret_cast<const uint4*>(eaw + eloc * 12);
        uint4 r1 = *reinterpret_cast<const uint4*>(eaw + eloc * 12 + 4);
        unsigned h2v[8] = {r0.x, r0.y, r0.z, r0.w, r1.x, r1.y, r1.z, r1.w};
        __half2 q0 = __floats2half2_rn(0.f, 0.f);
        __half2 q1 = q0;
#pragma unroll
        for (int m = 0; m < 8; m++) {
            __half2 tt = *reinterpret_cast<__half2*>(&h2v[m]);
            __half2 t0 = __low2half2(tt);
            __half2 t1 = __high2half2(tt);
            q0 = __hfma2(t0, wc[2 * m][0], q0);
            q1 = __hfma2(t0, wc[2 * m][1], q1);
            q0 = __hfma2(t1, wc[2 * m + 1][0], q0);
            q1 = __hfma2(t1, wc[2 * m + 1][1], q1);
        }
        float2 q0f = __half22float2(q0);
        float2 q1f = __half22float2(q1);

        float2 ps0 = __half22float2(*reinterpret_cast<__half2*>(&crs.x));
        float2 ps1 = __half22float2(*reinterpret_cast<__half2*>(&crs.y));
        float2 pd0 = __half22float2(*reinterpret_cast<__half2*>(&crd.x));
        float2 pd1 = __half22float2(*reinterpret_cast<__half2*>(&crd.y));

        float4 u4;
        u4.x = fmaxf(ps0.x + pd0.x + q0f.x + bb.x, 0.f);
        u4.y = fmaxf(ps0.y + pd0.y + q0f.y + bb.y, 0.f);
        u4.z = fmaxf(ps1.x + pd1.x + q1f.x + bb.z, 0.f);
        u4.w = fmaxf(ps1.y + pd1.y + q1f.y + bb.w, 0.f);
        float p0 = u4.x * w2a.x + u4.y * w2a.z + u4.z * w2b.x + u4.w * w2b.z;
        float p1 = u4.x * w2a.y + u4.y * w2a.w + u4.z * w2b.y + u4.w * w2b.w;

        p0 = row16_allreduce(p0);
        p1 = row16_allreduce(p1);

        int e = e0 + 4 * p + g;
        if (li == 0 && e < E) {
            float2 o = make_float2(p0 + c0, p1 + c1);
            *reinterpret_cast<float2*>(&out[(size_t)e * 2]) = o;
        }
    }
#undef ISSUE
}

static inline size_t align256(size_t x) { return (x + 255) & ~(size_t)255; }

extern "C" void kernel_launch(void* const* d_in, const int* in_sizes, int n_in,
                              void* d_out, int out_size, void* d_ws, size_t ws_size,
                              hipStream_t stream) {
    const float* x = (const float*)d_in[0];
    const int* ei = (const int*)d_in[1];
    const float* ea = (const float*)d_in[2];
    const float* W1 = (const float*)d_in[3];
    const float* b1 = (const float*)d_in[4];
    const float* W2 = (const float*)d_in[5];
    const float* b2 = (const float*)d_in[6];
    const float* Wm1 = (const float*)d_in[7];
    const float* bm1 = (const float*)d_in[8];
    const float* Wm2 = (const float*)d_in[9];
    const float* bm2 = (const float*)d_in[10];

    const int N = in_sizes[0] / 128;  // 50000
    const int E = in_sizes[1] / 2;    // 800000
    const int* src = ei;
    const int* dst = ei + E;
    float* out = (float*)d_out;

    const int NB = (N + 255) / 256;  // scan blocks (196)

    // ws layout (256B-aligned chunks)
    char* p = (char*)d_ws;
    int* cnt = (int*)p;        p += align256((size_t)N * 4);
    int* rank = (int*)p;       p += align256((size_t)E * 4);
    int* row_ptr = (int*)p;    p += align256((size_t)(N + 1) * 4);
    int* bsum = (int*)p;       p += align256((size_t)NB * 4);
    int* csr_src = (int*)p;    p += align256((size_t)E * 4);
    float* dinv = (float*)p;   p += align256((size_t)N * 4);
    __half* A16 = (__half*)p;  p += align256((size_t)N * 64 * 2);
    float* B = (float*)p;      p += align256((size_t)N * 64 * 4);
    __half* Ps16 = (__half*)p; p += align256((size_t)N * 64 * 2);
    __half* Pd16 = (__half*)p;

    // ---- CSR build (counting sort by dst; fill is atomic-free) ----
    hipMemsetAsync(cnt, 0, (size_t)N * sizeof(int), stream);
    k_count<<<(E + 255) / 256, 256, 0, stream>>>(dst, cnt, rank, E);
    k_bsum<<<NB, 256, 0, stream>>>(cnt, bsum, dinv, N);
    k_scanb<<<1, 256, 0, stream>>>(bsum, NB);
    k_scan3<<<NB, 256, 0, stream>>>(cnt, bsum, row_ptr, N, E);
    k_fill<<<(E + 255) / 256, 256, 0, stream>>>(src, dst, row_ptr, rank, csr_src, E);

    // ---- Layer 1 ----
    k_gemm<128, false, true, __half><<<(N + 63) / 64, 256, 0, stream>>>(
        x, W1, dinv, A16, N);
    k_agg<<<(N + 15) / 16, 256, 0, stream>>>(A16, row_ptr, csr_src, dinv, b1, B, N);

    // ---- Layer 2 ----
    k_gemm<64, true, true, __half><<<(N + 63) / 64, 256, 0, stream>>>(
        B, W2, dinv, A16, N);
    k_agg<<<(N + 15) / 16, 256, 0, stream>>>(A16, row_ptr, csr_src, dinv, b2, B, N);

    // ---- Edge MLP, decomposed ----
    k_proj<<<(N + 63) / 64, 256, 0, stream>>>(B, Wm1, Wm1 + 64 * 64, Ps16, Pd16, N);
    int waves = (E + 63) / 64;
    k_edge<<<(waves + 3) / 4, 256, 0, stream>>>(Ps16, Pd16, src, dst, ea,
                                                Wm1 + 128 * 64, bm1, Wm2, bm2,
                                                out, E);
}